// Round 1
// baseline (1498.100 us; speedup 1.0000x reference)
//
#include <hip/hip_runtime.h>
#include <math.h>

#define EPS 1e-5f
#define BNB 1e-4f

static __device__ __forceinline__ void atomAdd(float* p, float v) { unsafeAtomicAdd(p, v); }

// ---------------- column stats (sum, sumsq) ----------------
__global__ void k_stats(const float* __restrict__ X, int R, int C,
                        float* __restrict__ st, int scale_mode, const float* __restrict__ na)
{
  int T = gridDim.x * blockDim.x;
  int t = blockIdx.x * blockDim.x + threadIdx.x;
  int c = t % C;
  int r0 = t / C;
  int rs = T / C;
  float s = 0.f, s2 = 0.f;
  for (int r = r0; r < R; r += rs) {
    float sc = 1.f;
    if (scale_mode == 1) sc = na[r];
    else if (scale_mode == 2) sc = 1.f - na[r];
    float v = X[(size_t)r * C + c] * sc;
    s += v; s2 += v * v;
  }
  atomAdd(&st[c], s);
  atomAdd(&st[C + c], s2);
}

// fused stats for xc = na0*h and xo = (1-na0)*h in one pass over h
__global__ void k_stats2(const float* __restrict__ X, int R,
                         float* __restrict__ stA, float* __restrict__ stB,
                         const float* __restrict__ na)
{
  const int C = 128;
  int T = gridDim.x * blockDim.x;
  int t = blockIdx.x * blockDim.x + threadIdx.x;
  int c = t % C; int r0 = t / C; int rs = T / C;
  float sa = 0, sa2 = 0, sb = 0, sb2 = 0;
  for (int r = r0; r < R; r += rs) {
    float v = X[(size_t)r * C + c];
    float a = na[r] * v;
    float b = (1.f - na[r]) * v;
    sa += a; sa2 += a * a; sb += b; sb2 += b * b;
  }
  atomAdd(&stA[c], sa); atomAdd(&stA[C + c], sa2);
  atomAdd(&stB[c], sb); atomAdd(&stB[C + c], sb2);
}

// st layout: [0,C) sum, [C,2C) sumsq, [2C,3C) mean, [3C,4C) rsqrt(var+eps)
__global__ void k_finalize(float* st, int R, int C)
{
  int c = blockIdx.x * blockDim.x + threadIdx.x;
  if (c < C) {
    float m = st[c] / R;
    float v = st[C + c] / R - m * m;
    st[2 * C + c] = m;
    st[3 * C + c] = rsqrtf(v + EPS);
  }
}

// ---------------- BN-fused matmul: Out = act( BN(scale*A) @ W ), K=Ncol=128 ----------------
template<int ACT>
__global__ __launch_bounds__(256) void k_mm_bn(
    const float* __restrict__ A, const float* __restrict__ st,
    const float* __restrict__ W, float* __restrict__ Out,
    int Nrows, int scale_mode, const float* __restrict__ na)
{
  const int K = 128;
  __shared__ float lA[32][68];   // transposed A chunk [k][r], pad for alignment
  __shared__ float lW[32][128];
  int r0 = blockIdx.x * 64;
  int t = threadIdx.x;
  int tr = t >> 4, tc = t & 15;
  float acc[4][8] = {{0}};
  const float* mean = st + 2 * K;
  const float* inv  = st + 3 * K;
  int kl = t & 31, rl = t >> 5;
  int cl = t & 127, kl2 = t >> 7;
  for (int k0 = 0; k0 < K; k0 += 32) {
    #pragma unroll
    for (int j = 0; j < 8; j++) {
      int r = r0 + rl + 8 * j;
      float v = 0.f;
      if (r < Nrows) {
        float sc = 1.f;
        if (scale_mode == 1) sc = na[r];
        else if (scale_mode == 2) sc = 1.f - na[r];
        int k = k0 + kl;
        v = (sc * A[(size_t)r * K + k] - mean[k]) * inv[k] + BNB;
      }
      lA[kl][rl + 8 * j] = v;
    }
    #pragma unroll
    for (int j = 0; j < 16; j++)
      lW[kl2 + 2 * j][cl] = W[(size_t)(k0 + kl2 + 2 * j) * 128 + cl];
    __syncthreads();
    #pragma unroll
    for (int kk = 0; kk < 32; kk++) {
      float a[4], w[8];
      #pragma unroll
      for (int q = 0; q < 4; q++) a[q] = lA[kk][tr * 4 + q];
      #pragma unroll
      for (int n = 0; n < 4; n++) w[n] = lW[kk][tc * 4 + n];
      #pragma unroll
      for (int n = 0; n < 4; n++) w[4 + n] = lW[kk][64 + tc * 4 + n];
      #pragma unroll
      for (int q = 0; q < 4; q++)
        #pragma unroll
        for (int n = 0; n < 8; n++)
          acc[q][n] += a[q] * w[n];
    }
    __syncthreads();
  }
  #pragma unroll
  for (int q = 0; q < 4; q++) {
    int r = r0 + tr * 4 + q;
    if (r < Nrows) {
      #pragma unroll
      for (int n = 0; n < 8; n++) {
        float v = acc[q][n];
        if (ACT == 1) v = fmaxf(v, 0.f);
        int c = (n < 4) ? (tc * 4 + n) : (64 + tc * 4 + (n - 4));
        Out[(size_t)r * 128 + c] = v;
      }
    }
  }
}

// ---------------- graph structure ----------------
__global__ void k_hist_f(const int* __restrict__ idx, int E, float* __restrict__ deg)
{
  int e = blockIdx.x * blockDim.x + threadIdx.x;
  if (e < E) atomAdd(&deg[idx[e]], 1.f);
}
__global__ void k_hist_i(const int* __restrict__ idx, int E, int* __restrict__ cnt)
{
  int e = blockIdx.x * blockDim.x + threadIdx.x;
  if (e < E) atomicAdd(&cnt[idx[e]], 1);
}
__global__ void k_rsqrt1(const float* __restrict__ deg, float* __restrict__ dis, int Nn)
{
  int i = blockIdx.x * blockDim.x + threadIdx.x;
  if (i < Nn) dis[i] = rsqrtf(deg[i] + 1.f);  // +1 = self loop
}
// single-block exclusive scan (N up to ~64k fine)
__global__ void k_scan(const int* __restrict__ cnt, int Nn, int* __restrict__ row_start)
{
  __shared__ int sd[1024];
  __shared__ int srun;
  int t = threadIdx.x;
  if (t == 0) srun = 0;
  __syncthreads();
  for (int base = 0; base < Nn; base += 1024) {
    int v = (base + t < Nn) ? cnt[base + t] : 0;
    sd[t] = v;
    __syncthreads();
    for (int off = 1; off < 1024; off <<= 1) {
      int x = (t >= off) ? sd[t - off] : 0;
      __syncthreads();
      sd[t] += x;
      __syncthreads();
    }
    int incl = sd[t];
    int run = srun;
    if (base + t < Nn) row_start[base + t] = run + incl - v;
    __syncthreads();
    if (t == 1023) srun = run + incl;
    __syncthreads();
  }
  if (t == 0) row_start[Nn] = srun;
}
__global__ void k_fill(const int* __restrict__ src, const int* __restrict__ dst, int E,
                       const int* __restrict__ row_start, int* __restrict__ cnt,
                       int* __restrict__ csr_src, int* __restrict__ edgepos)
{
  int e = blockIdx.x * blockDim.x + threadIdx.x;
  if (e >= E) return;
  int d = dst[e];
  int k = atomicAdd(&cnt[d], 1);
  int pos = row_start[d] + k;
  csr_src[pos] = src[e];
  edgepos[e] = pos;
}

// ---------------- plain GCN propagate (gather), fused bias+selfloop+relu(+next BN stats) ----------------
template<int STATS>
__global__ __launch_bounds__(256) void k_gconv_plain(
    const float* __restrict__ Hw, const float* __restrict__ dis,
    const int* __restrict__ row_start, const int* __restrict__ csr_src,
    const float* __restrict__ bias, float* __restrict__ Out, int Nn,
    float* __restrict__ st)
{
  __shared__ float red[1024];
  int t = threadIdx.x;
  int lane = t & 63;
  int c0 = lane * 2;
  int wid = (blockIdx.x * 256 + t) >> 6;
  int nw = (gridDim.x * 256) >> 6;
  float b0 = bias[c0], b1 = bias[c0 + 1];
  float s0 = 0, s1 = 0, q0 = 0, q1 = 0;
  for (int i = wid; i < Nn; i += nw) {
    float di = dis[i];
    const float2 v = *(const float2*)(Hw + (size_t)i * 128 + c0);
    float ax = di * di * v.x + b0;
    float ay = di * di * v.y + b1;
    int jb = row_start[i], je = row_start[i + 1];
    for (int j = jb; j < je; j++) {
      int s = csr_src[j];
      float coef = dis[s] * di;
      const float2 u = *(const float2*)(Hw + (size_t)s * 128 + c0);
      ax += coef * u.x;
      ay += coef * u.y;
    }
    ax = fmaxf(ax, 0.f); ay = fmaxf(ay, 0.f);
    float2 o; o.x = ax; o.y = ay;
    *(float2*)(Out + (size_t)i * 128 + c0) = o;
    if (STATS) { s0 += ax; s1 += ay; q0 += ax * ax; q1 += ay * ay; }
  }
  if (STATS) {
    red[t] = s0; red[256 + t] = s1; red[512 + t] = q0; red[768 + t] = q1;
    __syncthreads();
    if (t < 64) {
      float a0 = red[t] + red[t + 64] + red[t + 128] + red[t + 192];
      float a1 = red[256 + t] + red[256 + t + 64] + red[256 + t + 128] + red[256 + t + 192];
      float a2 = red[512 + t] + red[512 + t + 64] + red[512 + t + 128] + red[512 + t + 192];
      float a3 = red[768 + t] + red[768 + t + 64] + red[768 + t + 128] + red[768 + t + 192];
      atomAdd(&st[2 * t], a0); atomAdd(&st[2 * t + 1], a1);
      atomAdd(&st[128 + 2 * t], a2); atomAdd(&st[128 + 2 * t + 1], a3);
    }
  }
}

// ---------------- weighted GCN propagate + elu + global_add_pool (batch is sorted) ----------------
template<int ATTMODE>  // 0: use att, 1: use 1-att
__global__ __launch_bounds__(256) void k_gconv_w_pool(
    const float* __restrict__ Hw, const float* __restrict__ disw,
    const int* __restrict__ row_start, const int* __restrict__ csr_src,
    const float* __restrict__ csr_att, const float* __restrict__ bias,
    const int* __restrict__ batch, float* __restrict__ outg, int Nn)
{
  int t = threadIdx.x;
  int lane = t & 63;
  int c0 = lane * 2;
  int wid = (blockIdx.x * 256 + t) >> 6;
  int nw = (gridDim.x * 256) >> 6;
  int chunk = (Nn + nw - 1) / nw;
  int i0 = wid * chunk;
  int i1 = min(Nn, i0 + chunk);
  float b0 = bias[c0], b1 = bias[c0 + 1];
  int curg = -1;
  float gx = 0.f, gy = 0.f;
  for (int i = i0; i < i1; i++) {
    float di = disw[i];
    const float2 v = *(const float2*)(Hw + (size_t)i * 128 + c0);
    float ax = di * di * v.x + b0;   // self loop has ew=1
    float ay = di * di * v.y + b1;
    int jb = row_start[i], je = row_start[i + 1];
    for (int j = jb; j < je; j++) {
      int s = csr_src[j];
      float a = csr_att[j];
      if (ATTMODE == 1) a = 1.f - a;
      float coef = disw[s] * a * di;
      const float2 u = *(const float2*)(Hw + (size_t)s * 128 + c0);
      ax += coef * u.x;
      ay += coef * u.y;
    }
    ax = ax > 0.f ? ax : expm1f(ax);
    ay = ay > 0.f ? ay : expm1f(ay);
    int g = batch[i];
    if (g != curg) {
      if (curg >= 0) { atomAdd(&outg[curg * 128 + c0], gx); atomAdd(&outg[curg * 128 + c0 + 1], gy); }
      curg = g; gx = ax; gy = ay;
    } else { gx += ax; gy += ay; }
  }
  if (curg >= 0) { atomAdd(&outg[curg * 128 + c0], gx); atomAdd(&outg[curg * 128 + c0 + 1], gy); }
}

// ---------------- per-node projections: P,Q (edge MLP halves) and hn = h@naW ----------------
__global__ __launch_bounds__(256) void k_pqhn(
    const float* __restrict__ H, const float* __restrict__ eW,
    const float* __restrict__ naW, float4* __restrict__ PQ,
    float2* __restrict__ hn, int Nn)
{
  __shared__ float w[128][6];
  int t = threadIdx.x;
  if (t < 128) {
    w[t][0] = eW[2 * t];       w[t][1] = eW[2 * t + 1];
    w[t][2] = eW[256 + 2 * t]; w[t][3] = eW[256 + 2 * t + 1];
    w[t][4] = naW[2 * t];      w[t][5] = naW[2 * t + 1];
  }
  __syncthreads();
  int lane = t & 63;
  int wid = (blockIdx.x * 256 + t) >> 6;
  int nw = (gridDim.x * 256) >> 6;
  for (int i = wid; i < Nn; i += nw) {
    const float2 h2 = *(const float2*)(H + (size_t)i * 128 + lane * 2);
    int k0 = lane * 2, k1 = lane * 2 + 1;
    float p0 = h2.x * w[k0][0] + h2.y * w[k1][0];
    float p1 = h2.x * w[k0][1] + h2.y * w[k1][1];
    float q0 = h2.x * w[k0][2] + h2.y * w[k1][2];
    float q1 = h2.x * w[k0][3] + h2.y * w[k1][3];
    float n0 = h2.x * w[k0][4] + h2.y * w[k1][4];
    float n1 = h2.x * w[k0][5] + h2.y * w[k1][5];
    #pragma unroll
    for (int o = 32; o > 0; o >>= 1) {
      p0 += __shfl_xor(p0, o); p1 += __shfl_xor(p1, o);
      q0 += __shfl_xor(q0, o); q1 += __shfl_xor(q1, o);
      n0 += __shfl_xor(n0, o); n1 += __shfl_xor(n1, o);
    }
    if (lane == 0) {
      PQ[i] = make_float4(p0, p1, q0, q1);
      hn[i] = make_float2(n0, n1);
    }
  }
}

// node-att propagate (2 channels, gather form)
__global__ void k_natt(const float2* __restrict__ hn, const float* __restrict__ dis,
                       const int* __restrict__ row_start, const int* __restrict__ csr_src,
                       const float* __restrict__ nab, float2* __restrict__ nlog, int Nn)
{
  int i = blockIdx.x * blockDim.x + threadIdx.x;
  if (i >= Nn) return;
  float di = dis[i];
  float2 h = hn[i];
  float a0 = di * di * h.x + nab[0];
  float a1 = di * di * h.y + nab[1];
  int jb = row_start[i], je = row_start[i + 1];
  for (int j = jb; j < je; j++) {
    int s = csr_src[j];
    float c = dis[s] * di;
    float2 hs = hn[s];
    a0 += c * hs.x;
    a1 += c * hs.y;
  }
  nlog[i] = make_float2(a0, a1);
}

// per-edge attention + weighted-degree accumulation
__global__ void k_edge(const int* __restrict__ src, const int* __restrict__ dst, int E,
                       const float4* __restrict__ PQ, const float* __restrict__ eb,
                       const int* __restrict__ edgepos, float* __restrict__ csr_att,
                       float* __restrict__ degc, float* __restrict__ dego)
{
  int e = blockIdx.x * blockDim.x + threadIdx.x;
  if (e >= E) return;
  int s = src[e], d = dst[e];
  float4 ps = PQ[s];
  float4 pd = PQ[d];
  float ld = (ps.x - ps.y) + (pd.z - pd.w) + (eb[0] - eb[1]);
  float att = 1.f / (1.f + expf(-ld));  // softmax over 2 = sigmoid(diff)
  csr_att[edgepos[e]] = att;
  atomAdd(&degc[s], att);
  atomAdd(&dego[s], 1.f - att);
}

__global__ void k_nodefin(const float* __restrict__ degc, const float* __restrict__ dego,
                          const float2* __restrict__ nlog, float* __restrict__ disc,
                          float* __restrict__ diso, float* __restrict__ na0, int Nn)
{
  int i = blockIdx.x * blockDim.x + threadIdx.x;
  if (i >= Nn) return;
  disc[i] = rsqrtf(degc[i] + 1.f);
  diso[i] = rsqrtf(dego[i] + 1.f);
  float2 l = nlog[i];
  na0[i] = 1.f / (1.f + expf(-(l.x - l.y)));
}

// ---------------- heads ----------------
template<int ACT>  // 0 none, 1 relu, 2 elu(elu(.))
__global__ void k_mm_head(const float* __restrict__ In, const float* __restrict__ st, int K,
                          const float* __restrict__ W, const float* __restrict__ bias,
                          float* __restrict__ Out, int M, int Ncol)
{
  int idx = blockIdx.x * blockDim.x + threadIdx.x;
  if (idx >= M * Ncol) return;
  int r = idx / Ncol, c = idx % Ncol;
  const float* mean = st + 2 * K;
  const float* inv  = st + 3 * K;
  float acc = bias[c];
  for (int k = 0; k < K; k++) {
    float a = (In[(size_t)r * K + k] - mean[k]) * inv[k] + BNB;
    acc += a * W[(size_t)k * Ncol + c];
  }
  if (ACT == 1) acc = fmaxf(acc, 0.f);
  if (ACT == 2) {
    acc = acc > 0.f ? acc : expm1f(acc);
    acc = acc > 0.f ? acc : expm1f(acc);
  }
  Out[idx] = acc;
}

__global__ void k_logits_lsm(const float* __restrict__ In, const float* __restrict__ st, int K,
                             const float* __restrict__ W, const float* __restrict__ bias,
                             float* __restrict__ Out, int M)
{
  int r = blockIdx.x * blockDim.x + threadIdx.x;
  if (r >= M) return;
  const float* mean = st + 2 * K;
  const float* inv  = st + 3 * K;
  float l[10];
  #pragma unroll
  for (int j = 0; j < 10; j++) l[j] = bias[j];
  for (int k = 0; k < K; k++) {
    float a = (In[(size_t)r * K + k] - mean[k]) * inv[k] + BNB;
    #pragma unroll
    for (int j = 0; j < 10; j++) l[j] += a * W[k * 10 + j];
  }
  float mx = l[0];
  #pragma unroll
  for (int j = 1; j < 10; j++) mx = fmaxf(mx, l[j]);
  float se = 0.f;
  #pragma unroll
  for (int j = 0; j < 10; j++) se += expf(l[j] - mx);
  float lse = mx + logf(se);
  #pragma unroll
  for (int j = 0; j < 10; j++) Out[r * 10 + j] = l[j] - lse;
}

__global__ void k_concat(const float* __restrict__ a, const float* __restrict__ b,
                         float* __restrict__ o)
{
  int idx = blockIdx.x * blockDim.x + threadIdx.x;
  if (idx >= 512 * 256) return;
  int r = idx >> 8, c = idx & 255;
  o[idx] = (c < 128) ? a[r * 128 + c] : b[r * 128 + (c - 128)];
}

// =====================================================================
extern "C" void kernel_launch(void* const* d_in, const int* in_sizes, int n_in,
                              void* d_out, int out_size, void* d_ws, size_t ws_size,
                              hipStream_t stream)
{
  (void)n_in; (void)out_size; (void)ws_size;
  const float* x      = (const float*)d_in[0];
  const float* W_feat = (const float*)d_in[1];
  const float* convW  = (const float*)d_in[2];
  const float* convB  = (const float*)d_in[3];
  const float* eW     = (const float*)d_in[4];
  const float* eb     = (const float*)d_in[5];
  const float* naW    = (const float*)d_in[6];
  const float* nab    = (const float*)d_in[7];
  const float* xcW    = (const float*)d_in[8];
  const float* xcb    = (const float*)d_in[9];
  const float* xoW    = (const float*)d_in[10];
  const float* xob    = (const float*)d_in[11];
  const float* cW1    = (const float*)d_in[12];
  const float* cb1    = (const float*)d_in[13];
  const float* cW2    = (const float*)d_in[14];
  const float* cb2    = (const float*)d_in[15];
  const float* oW1    = (const float*)d_in[16];
  const float* ob1    = (const float*)d_in[17];
  const float* oW2    = (const float*)d_in[18];
  const float* ob2    = (const float*)d_in[19];
  const float* coW1   = (const float*)d_in[20];
  const float* cob1   = (const float*)d_in[21];
  const float* coW2   = (const float*)d_in[22];
  const float* cob2   = (const float*)d_in[23];
  const int* esrc  = (const int*)d_in[24];
  const int* edst  = (const int*)d_in[25];
  const int* batch = (const int*)d_in[26];
  const int E = in_sizes[24];
  const int N = in_sizes[26];
  float* out = (float*)d_out;

  char* wp = (char*)d_ws;
  auto alloc = [&](size_t bytes) -> char* {
    char* p = wp;
    wp += (bytes + 255) & ~size_t(255);
    return p;
  };
  float*  A        = (float*)alloc((size_t)N * 128 * 4);
  float*  B        = (float*)alloc((size_t)N * 128 * 4);
  float*  dis      = (float*)alloc((size_t)N * 4);
  float*  disc     = (float*)alloc((size_t)N * 4);
  float*  diso     = (float*)alloc((size_t)N * 4);
  float*  na0      = (float*)alloc((size_t)N * 4);
  float4* PQ       = (float4*)alloc((size_t)N * 16);
  float2* hn       = (float2*)alloc((size_t)N * 8);
  float2* nlog     = (float2*)alloc((size_t)N * 8);
  float*  degA     = (float*)alloc((size_t)N * 4);
  float*  degB     = (float*)alloc((size_t)N * 4);
  int*    cnt      = (int*)alloc((size_t)N * 4);
  int*    row_start= (int*)alloc((size_t)(N + 1) * 4);
  int*    csr_src  = (int*)alloc((size_t)E * 4);
  float*  csr_att  = (float*)alloc((size_t)E * 4);
  int*    edgepos  = (int*)alloc((size_t)E * 4);
  float*  statA    = (float*)alloc(4 * 256 * 4);
  float*  statB    = (float*)alloc(4 * 256 * 4);
  float*  xc_g     = (float*)alloc(512 * 128 * 4);
  float*  xo_g     = (float*)alloc(512 * 128 * 4);
  float*  co_in    = (float*)alloc(512 * 256 * 4);
  float*  t1       = (float*)alloc(512 * 128 * 4);

  const int TPB = 256;
  int gE  = (E + TPB - 1) / TPB;
  int gN  = (N + TPB - 1) / TPB;
  int gMM = (N + 63) / 64;

  // ---- graph structure (deg/dis + CSR by dst) ----
  hipMemsetAsync(degA, 0, (size_t)N * 4, stream);
  k_hist_f<<<gE, TPB, 0, stream>>>(esrc, E, degA);
  k_rsqrt1<<<gN, TPB, 0, stream>>>(degA, dis, N);
  hipMemsetAsync(cnt, 0, (size_t)N * 4, stream);
  k_hist_i<<<gE, TPB, 0, stream>>>(edst, E, cnt);
  k_scan<<<1, 1024, 0, stream>>>(cnt, N, row_start);
  hipMemsetAsync(cnt, 0, (size_t)N * 4, stream);
  k_fill<<<gE, TPB, 0, stream>>>(esrc, edst, E, row_start, cnt, csr_src, edgepos);

  // ---- h = relu(BN(x) @ W_feat) ----
  hipMemsetAsync(statA, 0, 2 * 128 * 4, stream);
  k_stats<<<784, TPB, 0, stream>>>(x, N, 128, statA, 0, nullptr);
  k_finalize<<<1, 256, 0, stream>>>(statA, N, 128);
  k_mm_bn<1><<<gMM, TPB, 0, stream>>>(x, statA, W_feat, A, N, 0, nullptr);

  // ---- 3 GCN layers: h = relu(gcn(BN(h))) ----
  hipMemsetAsync(statA, 0, 2 * 128 * 4, stream);
  k_stats<<<784, TPB, 0, stream>>>(A, N, 128, statA, 0, nullptr);
  for (int l = 0; l < 3; l++) {
    k_finalize<<<1, 256, 0, stream>>>(statA, N, 128);
    k_mm_bn<0><<<gMM, TPB, 0, stream>>>(A, statA, convW + (size_t)l * 128 * 128, B, N, 0, nullptr);
    hipMemsetAsync(statA, 0, 2 * 128 * 4, stream);
    if (l < 2)
      k_gconv_plain<1><<<2048, TPB, 0, stream>>>(B, dis, row_start, csr_src, convB + l * 128, A, N, statA);
    else
      k_gconv_plain<0><<<2048, TPB, 0, stream>>>(B, dis, row_start, csr_src, convB + l * 128, A, N, nullptr);
  }

  // ---- attention (edge + node) ----
  k_pqhn<<<1024, TPB, 0, stream>>>(A, eW, naW, PQ, hn, N);
  k_natt<<<gN, TPB, 0, stream>>>(hn, dis, row_start, csr_src, nab, nlog, N);
  hipMemsetAsync(degA, 0, (size_t)N * 4, stream);
  hipMemsetAsync(degB, 0, (size_t)N * 4, stream);
  k_edge<<<gE, TPB, 0, stream>>>(esrc, edst, E, PQ, eb, edgepos, csr_att, degA, degB);
  k_nodefin<<<gN, TPB, 0, stream>>>(degA, degB, nlog, disc, diso, na0, N);

  // ---- xc / xo BN stats (fused single pass over h) ----
  hipMemsetAsync(statA, 0, 2 * 128 * 4, stream);
  hipMemsetAsync(statB, 0, 2 * 128 * 4, stream);
  k_stats2<<<784, TPB, 0, stream>>>(A, N, statA, statB, na0);
  k_finalize<<<1, 256, 0, stream>>>(statA, N, 128);
  k_finalize<<<1, 256, 0, stream>>>(statB, N, 128);

  // ---- xc branch ----
  k_mm_bn<0><<<gMM, TPB, 0, stream>>>(A, statA, xcW, B, N, 1, na0);
  hipMemsetAsync(xc_g, 0, 512 * 128 * 4, stream);
  k_gconv_w_pool<0><<<2048, TPB, 0, stream>>>(B, disc, row_start, csr_src, csr_att, xcb, batch, xc_g, N);
  // ---- xo branch ----
  k_mm_bn<0><<<gMM, TPB, 0, stream>>>(A, statB, xoW, B, N, 2, na0);
  hipMemsetAsync(xo_g, 0, 512 * 128 * 4, stream);
  k_gconv_w_pool<1><<<2048, TPB, 0, stream>>>(B, diso, row_start, csr_src, csr_att, xob, batch, xo_g, N);

  // ---- head C ----
  hipMemsetAsync(statA, 0, 2 * 128 * 4, stream);
  k_stats<<<16, TPB, 0, stream>>>(xc_g, 512, 128, statA, 0, nullptr);
  k_finalize<<<1, 256, 0, stream>>>(statA, 512, 128);
  k_mm_head<1><<<(512 * 128 + TPB - 1) / TPB, TPB, 0, stream>>>(xc_g, statA, 128, cW1, cb1, t1, 512, 128);
  hipMemsetAsync(statB, 0, 2 * 128 * 4, stream);
  k_stats<<<16, TPB, 0, stream>>>(t1, 512, 128, statB, 0, nullptr);
  k_finalize<<<1, 256, 0, stream>>>(statB, 512, 128);
  k_logits_lsm<<<2, TPB, 0, stream>>>(t1, statB, 128, cW2, cb2, out, 512);

  // ---- head O ----
  hipMemsetAsync(statA, 0, 2 * 128 * 4, stream);
  k_stats<<<16, TPB, 0, stream>>>(xo_g, 512, 128, statA, 0, nullptr);
  k_finalize<<<1, 256, 0, stream>>>(statA, 512, 128);
  k_mm_head<1><<<(512 * 128 + TPB - 1) / TPB, TPB, 0, stream>>>(xo_g, statA, 128, oW1, ob1, t1, 512, 128);
  hipMemsetAsync(statB, 0, 2 * 128 * 4, stream);
  k_stats<<<16, TPB, 0, stream>>>(t1, 512, 128, statB, 0, nullptr);
  k_finalize<<<1, 256, 0, stream>>>(statB, 512, 128);
  k_logits_lsm<<<2, TPB, 0, stream>>>(t1, statB, 128, oW2, ob2, out + 5120, 512);

  // ---- head CO ----
  k_concat<<<512, TPB, 0, stream>>>(xc_g, xo_g, co_in);
  hipMemsetAsync(statA, 0, 2 * 256 * 4, stream);
  k_stats<<<16, TPB, 0, stream>>>(co_in, 512, 256, statA, 0, nullptr);
  k_finalize<<<1, 256, 0, stream>>>(statA, 512, 256);
  k_mm_head<2><<<(512 * 128 + TPB - 1) / TPB, TPB, 0, stream>>>(co_in, statA, 256, coW1, cob1, t1, 512, 128);
  hipMemsetAsync(statB, 0, 2 * 128 * 4, stream);
  k_stats<<<16, TPB, 0, stream>>>(t1, 512, 128, statB, 0, nullptr);
  k_finalize<<<1, 256, 0, stream>>>(statB, 512, 128);
  k_logits_lsm<<<2, TPB, 0, stream>>>(t1, statB, 128, coW2, cob2, out + 10240, 512);
}

// Round 2
// 1433.301 us; speedup vs baseline: 1.0452x; 1.0452x over previous
//
#include <hip/hip_runtime.h>
#include <math.h>

#define EPS 1e-5f
#define BNB 1e-4f

static __device__ __forceinline__ void atomAdd(float* p, float v) { unsafeAtomicAdd(p, v); }

// ---------------- column stats (sum, sumsq) ----------------
__global__ void k_stats(const float* __restrict__ X, int R, int C,
                        float* __restrict__ st, int scale_mode, const float* __restrict__ na)
{
  int T = gridDim.x * blockDim.x;
  int t = blockIdx.x * blockDim.x + threadIdx.x;
  int c = t % C;
  int r0 = t / C;
  int rs = T / C;
  float s = 0.f, s2 = 0.f;
  for (int r = r0; r < R; r += rs) {
    float sc = 1.f;
    if (scale_mode == 1) sc = na[r];
    else if (scale_mode == 2) sc = 1.f - na[r];
    float v = X[(size_t)r * C + c] * sc;
    s += v; s2 += v * v;
  }
  atomAdd(&st[c], s);
  atomAdd(&st[C + c], s2);
}

// fused stats for xc = na0*h and xo = (1-na0)*h in one pass over h
__global__ void k_stats2(const float* __restrict__ X, int R,
                         float* __restrict__ stA, float* __restrict__ stB,
                         const float* __restrict__ na)
{
  const int C = 128;
  int T = gridDim.x * blockDim.x;
  int t = blockIdx.x * blockDim.x + threadIdx.x;
  int c = t % C; int r0 = t / C; int rs = T / C;
  float sa = 0, sa2 = 0, sb = 0, sb2 = 0;
  for (int r = r0; r < R; r += rs) {
    float v = X[(size_t)r * C + c];
    float a = na[r] * v;
    float b = (1.f - na[r]) * v;
    sa += a; sa2 += a * a; sb += b; sb2 += b * b;
  }
  atomAdd(&stA[c], sa); atomAdd(&stA[C + c], sa2);
  atomAdd(&stB[c], sb); atomAdd(&stB[C + c], sb2);
}

// st layout: [0,C) sum, [C,2C) sumsq, [2C,3C) mean, [3C,4C) rsqrt(var+eps)
__global__ void k_finalize(float* st, int R, int C)
{
  int c = blockIdx.x * blockDim.x + threadIdx.x;
  if (c < C) {
    float m = st[c] / R;
    float v = st[C + c] / R - m * m;
    st[2 * C + c] = m;
    st[3 * C + c] = rsqrtf(v + EPS);
  }
}

// ---------------- BN-fused matmul: Out = act( BN(scale*A) @ W ), K=Ncol=128 ----------------
template<int ACT>
__global__ __launch_bounds__(256) void k_mm_bn(
    const float* __restrict__ A, const float* __restrict__ st,
    const float* __restrict__ W, float* __restrict__ Out,
    int Nrows, int scale_mode, const float* __restrict__ na)
{
  const int K = 128;
  __shared__ float lA[32][68];
  __shared__ float lW[32][128];
  int r0 = blockIdx.x * 64;
  int t = threadIdx.x;
  int tr = t >> 4, tc = t & 15;
  float acc[4][8] = {{0}};
  const float* mean = st + 2 * K;
  const float* inv  = st + 3 * K;
  int kl = t & 31, rl = t >> 5;
  int cl = t & 127, kl2 = t >> 7;
  for (int k0 = 0; k0 < K; k0 += 32) {
    #pragma unroll
    for (int j = 0; j < 8; j++) {
      int r = r0 + rl + 8 * j;
      float v = 0.f;
      if (r < Nrows) {
        float sc = 1.f;
        if (scale_mode == 1) sc = na[r];
        else if (scale_mode == 2) sc = 1.f - na[r];
        int k = k0 + kl;
        v = (sc * A[(size_t)r * K + k] - mean[k]) * inv[k] + BNB;
      }
      lA[kl][rl + 8 * j] = v;
    }
    #pragma unroll
    for (int j = 0; j < 16; j++)
      lW[kl2 + 2 * j][cl] = W[(size_t)(k0 + kl2 + 2 * j) * 128 + cl];
    __syncthreads();
    #pragma unroll
    for (int kk = 0; kk < 32; kk++) {
      float a[4], w[8];
      #pragma unroll
      for (int q = 0; q < 4; q++) a[q] = lA[kk][tr * 4 + q];
      #pragma unroll
      for (int n = 0; n < 4; n++) w[n] = lW[kk][tc * 4 + n];
      #pragma unroll
      for (int n = 0; n < 4; n++) w[4 + n] = lW[kk][64 + tc * 4 + n];
      #pragma unroll
      for (int q = 0; q < 4; q++)
        #pragma unroll
        for (int n = 0; n < 8; n++)
          acc[q][n] += a[q] * w[n];
    }
    __syncthreads();
  }
  #pragma unroll
  for (int q = 0; q < 4; q++) {
    int r = r0 + tr * 4 + q;
    if (r < Nrows) {
      #pragma unroll
      for (int n = 0; n < 8; n++) {
        float v = acc[q][n];
        if (ACT == 1) v = fmaxf(v, 0.f);
        int c = (n < 4) ? (tc * 4 + n) : (64 + tc * 4 + (n - 4));
        Out[(size_t)r * 128 + c] = v;
      }
    }
  }
}

// ---------------- graph structure ----------------
__global__ void k_hist_f(const int* __restrict__ idx, int E, float* __restrict__ deg)
{
  int e = blockIdx.x * blockDim.x + threadIdx.x;
  if (e < E) atomAdd(&deg[idx[e]], 1.f);
}
__global__ void k_hist_i(const int* __restrict__ idx, int E, int* __restrict__ cnt)
{
  int e = blockIdx.x * blockDim.x + threadIdx.x;
  if (e < E) atomicAdd(&cnt[idx[e]], 1);
}
// dis = rsqrt(deg+1), dis2 = self coef
__global__ void k_rsqrt1(const float* __restrict__ deg, float* __restrict__ dis,
                         float* __restrict__ dis2, int Nn)
{
  int i = blockIdx.x * blockDim.x + threadIdx.x;
  if (i < Nn) {
    float d = rsqrtf(deg[i] + 1.f);
    dis[i] = d;
    dis2[i] = d * d;
  }
}
// single-block exclusive scan
__global__ void k_scan(const int* __restrict__ cnt, int Nn, int* __restrict__ row_start)
{
  __shared__ int sd[1024];
  __shared__ int srun;
  int t = threadIdx.x;
  if (t == 0) srun = 0;
  __syncthreads();
  for (int base = 0; base < Nn; base += 1024) {
    int v = (base + t < Nn) ? cnt[base + t] : 0;
    sd[t] = v;
    __syncthreads();
    for (int off = 1; off < 1024; off <<= 1) {
      int x = (t >= off) ? sd[t - off] : 0;
      __syncthreads();
      sd[t] += x;
      __syncthreads();
    }
    int incl = sd[t];
    int run = srun;
    if (base + t < Nn) row_start[base + t] = run + incl - v;
    __syncthreads();
    if (t == 1023) srun = run + incl;
    __syncthreads();
  }
  if (t == 0) row_start[Nn] = srun;
}
// fill CSR: src index + plain normalized coef dis[s]*dis[d]
__global__ void k_fill(const int* __restrict__ src, const int* __restrict__ dst, int E,
                       const int* __restrict__ row_start, int* __restrict__ cnt,
                       const float* __restrict__ dis,
                       int* __restrict__ csr_src, float* __restrict__ csr_coef,
                       int* __restrict__ edgepos)
{
  int e = blockIdx.x * blockDim.x + threadIdx.x;
  if (e >= E) return;
  int d = dst[e];
  int s = src[e];
  int k = atomicAdd(&cnt[d], 1);
  int pos = row_start[d] + k;
  csr_src[pos] = s;
  csr_coef[pos] = dis[s] * dis[d];
  edgepos[e] = pos;
}

// ---------------- shared gather core: 8-way ILP row accumulation ----------------
// invalid lanes hold idx=0, coef=0; overshoot groups read row 0 (cached) * 0.
__device__ __forceinline__ void gather_rows(
    const float* __restrict__ Hw, int c0, int jb, int je,
    const int* __restrict__ csr_src, const float* __restrict__ coef,
    float& ax, float& ay)
{
  int lane = threadIdx.x & 63;
  for (int base = jb; base < je; base += 64) {
    int nj = min(je - base, 64);
    int idx = 0; float cf = 0.f;
    if (lane < nj) {
      idx = csr_src[base + lane];
      cf  = coef[base + lane];
    }
    for (int j = 0; j < nj; j += 8) {
      int i0 = __shfl(idx, j + 0), i1 = __shfl(idx, j + 1);
      int i2 = __shfl(idx, j + 2), i3 = __shfl(idx, j + 3);
      int i4 = __shfl(idx, j + 4), i5 = __shfl(idx, j + 5);
      int i6 = __shfl(idx, j + 6), i7 = __shfl(idx, j + 7);
      float f0 = __shfl(cf, j + 0), f1 = __shfl(cf, j + 1);
      float f2 = __shfl(cf, j + 2), f3 = __shfl(cf, j + 3);
      float f4 = __shfl(cf, j + 4), f5 = __shfl(cf, j + 5);
      float f6 = __shfl(cf, j + 6), f7 = __shfl(cf, j + 7);
      const float2 u0 = *(const float2*)(Hw + (size_t)i0 * 128 + c0);
      const float2 u1 = *(const float2*)(Hw + (size_t)i1 * 128 + c0);
      const float2 u2 = *(const float2*)(Hw + (size_t)i2 * 128 + c0);
      const float2 u3 = *(const float2*)(Hw + (size_t)i3 * 128 + c0);
      const float2 u4 = *(const float2*)(Hw + (size_t)i4 * 128 + c0);
      const float2 u5 = *(const float2*)(Hw + (size_t)i5 * 128 + c0);
      const float2 u6 = *(const float2*)(Hw + (size_t)i6 * 128 + c0);
      const float2 u7 = *(const float2*)(Hw + (size_t)i7 * 128 + c0);
      ax = fmaf(f0, u0.x, ax); ay = fmaf(f0, u0.y, ay);
      ax = fmaf(f1, u1.x, ax); ay = fmaf(f1, u1.y, ay);
      ax = fmaf(f2, u2.x, ax); ay = fmaf(f2, u2.y, ay);
      ax = fmaf(f3, u3.x, ax); ay = fmaf(f3, u3.y, ay);
      ax = fmaf(f4, u4.x, ax); ay = fmaf(f4, u4.y, ay);
      ax = fmaf(f5, u5.x, ax); ay = fmaf(f5, u5.y, ay);
      ax = fmaf(f6, u6.x, ax); ay = fmaf(f6, u6.y, ay);
      ax = fmaf(f7, u7.x, ax); ay = fmaf(f7, u7.y, ay);
    }
  }
}

// ---------------- plain GCN propagate, fused bias+selfloop+relu(+next BN stats) ----------------
template<int STATS>
__global__ __launch_bounds__(256) void k_gconv_plain(
    const float* __restrict__ Hw, const float* __restrict__ selfc,
    const int* __restrict__ row_start, const int* __restrict__ csr_src,
    const float* __restrict__ csr_coef,
    const float* __restrict__ bias, float* __restrict__ Out, int Nn,
    float* __restrict__ st)
{
  __shared__ float red[1024];
  int t = threadIdx.x;
  int lane = t & 63;
  int c0 = lane * 2;
  int wid = (blockIdx.x * 256 + t) >> 6;
  int nw = (gridDim.x * 256) >> 6;
  float b0 = bias[c0], b1 = bias[c0 + 1];
  float s0 = 0, s1 = 0, q0 = 0, q1 = 0;
  for (int i = wid; i < Nn; i += nw) {
    float sc = selfc[i];
    const float2 v = *(const float2*)(Hw + (size_t)i * 128 + c0);
    float ax = sc * v.x + b0;
    float ay = sc * v.y + b1;
    gather_rows(Hw, c0, row_start[i], row_start[i + 1], csr_src, csr_coef, ax, ay);
    ax = fmaxf(ax, 0.f); ay = fmaxf(ay, 0.f);
    float2 o; o.x = ax; o.y = ay;
    *(float2*)(Out + (size_t)i * 128 + c0) = o;
    if (STATS) { s0 += ax; s1 += ay; q0 += ax * ax; q1 += ay * ay; }
  }
  if (STATS) {
    red[t] = s0; red[256 + t] = s1; red[512 + t] = q0; red[768 + t] = q1;
    __syncthreads();
    if (t < 64) {
      float a0 = red[t] + red[t + 64] + red[t + 128] + red[t + 192];
      float a1 = red[256 + t] + red[256 + t + 64] + red[256 + t + 128] + red[256 + t + 192];
      float a2 = red[512 + t] + red[512 + t + 64] + red[512 + t + 128] + red[512 + t + 192];
      float a3 = red[768 + t] + red[768 + t + 64] + red[768 + t + 128] + red[768 + t + 192];
      atomAdd(&st[2 * t], a0); atomAdd(&st[2 * t + 1], a1);
      atomAdd(&st[128 + 2 * t], a2); atomAdd(&st[128 + 2 * t + 1], a3);
    }
  }
}

// ---------------- weighted GCN propagate + elu + global_add_pool (batch sorted) ----------------
__global__ __launch_bounds__(256) void k_gconv_w_pool(
    const float* __restrict__ Hw, const float* __restrict__ selfc,
    const int* __restrict__ row_start, const int* __restrict__ csr_src,
    const float* __restrict__ coef, const float* __restrict__ bias,
    const int* __restrict__ batch, float* __restrict__ outg, int Nn)
{
  int t = threadIdx.x;
  int lane = t & 63;
  int c0 = lane * 2;
  int wid = (blockIdx.x * 256 + t) >> 6;
  int nw = (gridDim.x * 256) >> 6;
  int chunk = (Nn + nw - 1) / nw;
  int i0 = wid * chunk;
  int i1 = min(Nn, i0 + chunk);
  float b0 = bias[c0], b1 = bias[c0 + 1];
  int curg = -1;
  float gx = 0.f, gy = 0.f;
  for (int i = i0; i < i1; i++) {
    float sc = selfc[i];
    const float2 v = *(const float2*)(Hw + (size_t)i * 128 + c0);
    float ax = sc * v.x + b0;
    float ay = sc * v.y + b1;
    gather_rows(Hw, c0, row_start[i], row_start[i + 1], csr_src, coef, ax, ay);
    ax = ax > 0.f ? ax : expm1f(ax);
    ay = ay > 0.f ? ay : expm1f(ay);
    int g = batch[i];
    if (g != curg) {
      if (curg >= 0) { atomAdd(&outg[curg * 128 + c0], gx); atomAdd(&outg[curg * 128 + c0 + 1], gy); }
      curg = g; gx = ax; gy = ay;
    } else { gx += ax; gy += ay; }
  }
  if (curg >= 0) { atomAdd(&outg[curg * 128 + c0], gx); atomAdd(&outg[curg * 128 + c0 + 1], gy); }
}

// ---------------- per-node projections: P,Q (edge MLP halves) and hn = h@naW ----------------
__global__ __launch_bounds__(256) void k_pqhn(
    const float* __restrict__ H, const float* __restrict__ eW,
    const float* __restrict__ naW, float4* __restrict__ PQ,
    float2* __restrict__ hn, int Nn)
{
  __shared__ float w[128][6];
  int t = threadIdx.x;
  if (t < 128) {
    w[t][0] = eW[2 * t];       w[t][1] = eW[2 * t + 1];
    w[t][2] = eW[256 + 2 * t]; w[t][3] = eW[256 + 2 * t + 1];
    w[t][4] = naW[2 * t];      w[t][5] = naW[2 * t + 1];
  }
  __syncthreads();
  int lane = t & 63;
  int wid = (blockIdx.x * 256 + t) >> 6;
  int nw = (gridDim.x * 256) >> 6;
  for (int i = wid; i < Nn; i += nw) {
    const float2 h2 = *(const float2*)(H + (size_t)i * 128 + lane * 2);
    int k0 = lane * 2, k1 = lane * 2 + 1;
    float p0 = h2.x * w[k0][0] + h2.y * w[k1][0];
    float p1 = h2.x * w[k0][1] + h2.y * w[k1][1];
    float q0 = h2.x * w[k0][2] + h2.y * w[k1][2];
    float q1 = h2.x * w[k0][3] + h2.y * w[k1][3];
    float n0 = h2.x * w[k0][4] + h2.y * w[k1][4];
    float n1 = h2.x * w[k0][5] + h2.y * w[k1][5];
    #pragma unroll
    for (int o = 32; o > 0; o >>= 1) {
      p0 += __shfl_xor(p0, o); p1 += __shfl_xor(p1, o);
      q0 += __shfl_xor(q0, o); q1 += __shfl_xor(q1, o);
      n0 += __shfl_xor(n0, o); n1 += __shfl_xor(n1, o);
    }
    if (lane == 0) {
      PQ[i] = make_float4(p0, p1, q0, q1);
      hn[i] = make_float2(n0, n1);
    }
  }
}

// node-att propagate (2 channels, gather form), uses plain csr_coef
__global__ void k_natt(const float2* __restrict__ hn, const float* __restrict__ selfc,
                       const int* __restrict__ row_start, const int* __restrict__ csr_src,
                       const float* __restrict__ csr_coef,
                       const float* __restrict__ nab, float2* __restrict__ nlog, int Nn)
{
  int i = blockIdx.x * blockDim.x + threadIdx.x;
  if (i >= Nn) return;
  float sc = selfc[i];
  float2 h = hn[i];
  float a0 = sc * h.x + nab[0];
  float a1 = sc * h.y + nab[1];
  int jb = row_start[i], je = row_start[i + 1];
  for (int j = jb; j < je; j++) {
    int s = csr_src[j];
    float c = csr_coef[j];
    float2 hs = hn[s];
    a0 += c * hs.x;
    a1 += c * hs.y;
  }
  nlog[i] = make_float2(a0, a1);
}

// per-edge attention (edge order) + weighted-degree accumulation
__global__ void k_edge(const int* __restrict__ src, const int* __restrict__ dst, int E,
                       const float4* __restrict__ PQ, const float* __restrict__ eb,
                       float* __restrict__ attE,
                       float* __restrict__ degc, float* __restrict__ dego)
{
  int e = blockIdx.x * blockDim.x + threadIdx.x;
  if (e >= E) return;
  int s = src[e], d = dst[e];
  float4 ps = PQ[s];
  float4 pd = PQ[d];
  float ld = (ps.x - ps.y) + (pd.z - pd.w) + (eb[0] - eb[1]);
  float att = 1.f / (1.f + expf(-ld));
  attE[e] = att;
  atomAdd(&degc[s], att);
  atomAdd(&dego[s], 1.f - att);
}

__global__ void k_nodefin(const float* __restrict__ degc, const float* __restrict__ dego,
                          const float2* __restrict__ nlog,
                          float* __restrict__ disc, float* __restrict__ diso,
                          float* __restrict__ selfcc, float* __restrict__ selfco,
                          float* __restrict__ na0, int Nn)
{
  int i = blockIdx.x * blockDim.x + threadIdx.x;
  if (i >= Nn) return;
  float dc = rsqrtf(degc[i] + 1.f);
  float dd = rsqrtf(dego[i] + 1.f);
  disc[i] = dc; diso[i] = dd;
  selfcc[i] = dc * dc; selfco[i] = dd * dd;
  float2 l = nlog[i];
  na0[i] = 1.f / (1.f + expf(-(l.x - l.y)));
}

// per-edge weighted coefs into CSR order
__global__ void k_edge2(const int* __restrict__ src, const int* __restrict__ dst, int E,
                        const float* __restrict__ attE, const int* __restrict__ edgepos,
                        const float* __restrict__ disc, const float* __restrict__ diso,
                        float* __restrict__ coefc, float* __restrict__ coefo)
{
  int e = blockIdx.x * blockDim.x + threadIdx.x;
  if (e >= E) return;
  int s = src[e], d = dst[e];
  int pos = edgepos[e];
  float att = attE[e];
  coefc[pos] = disc[s] * att * disc[d];
  coefo[pos] = diso[s] * (1.f - att) * diso[d];
}

// ---------------- heads ----------------
template<int ACT>
__global__ void k_mm_head(const float* __restrict__ In, const float* __restrict__ st, int K,
                          const float* __restrict__ W, const float* __restrict__ bias,
                          float* __restrict__ Out, int M, int Ncol)
{
  int idx = blockIdx.x * blockDim.x + threadIdx.x;
  if (idx >= M * Ncol) return;
  int r = idx / Ncol, c = idx % Ncol;
  const float* mean = st + 2 * K;
  const float* inv  = st + 3 * K;
  float acc = bias[c];
  for (int k = 0; k < K; k++) {
    float a = (In[(size_t)r * K + k] - mean[k]) * inv[k] + BNB;
    acc += a * W[(size_t)k * Ncol + c];
  }
  if (ACT == 1) acc = fmaxf(acc, 0.f);
  if (ACT == 2) {
    acc = acc > 0.f ? acc : expm1f(acc);
    acc = acc > 0.f ? acc : expm1f(acc);
  }
  Out[idx] = acc;
}

__global__ void k_logits_lsm(const float* __restrict__ In, const float* __restrict__ st, int K,
                             const float* __restrict__ W, const float* __restrict__ bias,
                             float* __restrict__ Out, int M)
{
  int r = blockIdx.x * blockDim.x + threadIdx.x;
  if (r >= M) return;
  const float* mean = st + 2 * K;
  const float* inv  = st + 3 * K;
  float l[10];
  #pragma unroll
  for (int j = 0; j < 10; j++) l[j] = bias[j];
  for (int k = 0; k < K; k++) {
    float a = (In[(size_t)r * K + k] - mean[k]) * inv[k] + BNB;
    #pragma unroll
    for (int j = 0; j < 10; j++) l[j] += a * W[k * 10 + j];
  }
  float mx = l[0];
  #pragma unroll
  for (int j = 1; j < 10; j++) mx = fmaxf(mx, l[j]);
  float se = 0.f;
  #pragma unroll
  for (int j = 0; j < 10; j++) se += expf(l[j] - mx);
  float lse = mx + logf(se);
  #pragma unroll
  for (int j = 0; j < 10; j++) Out[r * 10 + j] = l[j] - lse;
}

__global__ void k_concat(const float* __restrict__ a, const float* __restrict__ b,
                         float* __restrict__ o)
{
  int idx = blockIdx.x * blockDim.x + threadIdx.x;
  if (idx >= 512 * 256) return;
  int r = idx >> 8, c = idx & 255;
  o[idx] = (c < 128) ? a[r * 128 + c] : b[r * 128 + (c - 128)];
}

// =====================================================================
extern "C" void kernel_launch(void* const* d_in, const int* in_sizes, int n_in,
                              void* d_out, int out_size, void* d_ws, size_t ws_size,
                              hipStream_t stream)
{
  (void)n_in; (void)out_size; (void)ws_size;
  const float* x      = (const float*)d_in[0];
  const float* W_feat = (const float*)d_in[1];
  const float* convW  = (const float*)d_in[2];
  const float* convB  = (const float*)d_in[3];
  const float* eW     = (const float*)d_in[4];
  const float* eb     = (const float*)d_in[5];
  const float* naW    = (const float*)d_in[6];
  const float* nab    = (const float*)d_in[7];
  const float* xcW    = (const float*)d_in[8];
  const float* xcb    = (const float*)d_in[9];
  const float* xoW    = (const float*)d_in[10];
  const float* xob    = (const float*)d_in[11];
  const float* cW1    = (const float*)d_in[12];
  const float* cb1    = (const float*)d_in[13];
  const float* cW2    = (const float*)d_in[14];
  const float* cb2    = (const float*)d_in[15];
  const float* oW1    = (const float*)d_in[16];
  const float* ob1    = (const float*)d_in[17];
  const float* oW2    = (const float*)d_in[18];
  const float* ob2    = (const float*)d_in[19];
  const float* coW1   = (const float*)d_in[20];
  const float* cob1   = (const float*)d_in[21];
  const float* coW2   = (const float*)d_in[22];
  const float* cob2   = (const float*)d_in[23];
  const int* esrc  = (const int*)d_in[24];
  const int* edst  = (const int*)d_in[25];
  const int* batch = (const int*)d_in[26];
  const int E = in_sizes[24];
  const int N = in_sizes[26];
  float* out = (float*)d_out;

  char* wp = (char*)d_ws;
  auto alloc = [&](size_t bytes) -> char* {
    char* p = wp;
    wp += (bytes + 255) & ~size_t(255);
    return p;
  };
  float*  A        = (float*)alloc((size_t)N * 128 * 4);
  float*  B        = (float*)alloc((size_t)N * 128 * 4);
  float*  dis      = (float*)alloc((size_t)N * 4);
  float*  dis2     = (float*)alloc((size_t)N * 4);
  float*  disc     = (float*)alloc((size_t)N * 4);
  float*  diso     = (float*)alloc((size_t)N * 4);
  float*  selfcc   = (float*)alloc((size_t)N * 4);
  float*  selfco   = (float*)alloc((size_t)N * 4);
  float*  na0      = (float*)alloc((size_t)N * 4);
  float4* PQ       = (float4*)alloc((size_t)N * 16);
  float2* hn       = (float2*)alloc((size_t)N * 8);
  float2* nlog     = (float2*)alloc((size_t)N * 8);
  float*  degA     = (float*)alloc((size_t)N * 4);
  float*  degB     = (float*)alloc((size_t)N * 4);
  int*    cnt      = (int*)alloc((size_t)N * 4);
  int*    row_start= (int*)alloc((size_t)(N + 1) * 4);
  int*    csr_src  = (int*)alloc((size_t)E * 4);
  float*  csr_coef = (float*)alloc((size_t)E * 4);
  float*  coefc    = (float*)alloc((size_t)E * 4);
  float*  coefo    = (float*)alloc((size_t)E * 4);
  float*  attE     = (float*)alloc((size_t)E * 4);
  int*    edgepos  = (int*)alloc((size_t)E * 4);
  float*  statA    = (float*)alloc(4 * 256 * 4);
  float*  statB    = (float*)alloc(4 * 256 * 4);
  float*  xc_g     = (float*)alloc(512 * 128 * 4);
  float*  xo_g     = (float*)alloc(512 * 128 * 4);
  float*  co_in    = (float*)alloc(512 * 256 * 4);
  float*  t1       = (float*)alloc(512 * 128 * 4);

  const int TPB = 256;
  int gE  = (E + TPB - 1) / TPB;
  int gN  = (N + TPB - 1) / TPB;
  int gMM = (N + 63) / 64;

  // ---- graph structure (deg/dis + CSR by dst, with plain coefs) ----
  hipMemsetAsync(degA, 0, (size_t)N * 4, stream);
  k_hist_f<<<gE, TPB, 0, stream>>>(esrc, E, degA);
  k_rsqrt1<<<gN, TPB, 0, stream>>>(degA, dis, dis2, N);
  hipMemsetAsync(cnt, 0, (size_t)N * 4, stream);
  k_hist_i<<<gE, TPB, 0, stream>>>(edst, E, cnt);
  k_scan<<<1, 1024, 0, stream>>>(cnt, N, row_start);
  hipMemsetAsync(cnt, 0, (size_t)N * 4, stream);
  k_fill<<<gE, TPB, 0, stream>>>(esrc, edst, E, row_start, cnt, dis, csr_src, csr_coef, edgepos);

  // ---- h = relu(BN(x) @ W_feat) ----
  hipMemsetAsync(statA, 0, 2 * 128 * 4, stream);
  k_stats<<<784, TPB, 0, stream>>>(x, N, 128, statA, 0, nullptr);
  k_finalize<<<1, 256, 0, stream>>>(statA, N, 128);
  k_mm_bn<1><<<gMM, TPB, 0, stream>>>(x, statA, W_feat, A, N, 0, nullptr);

  // ---- 3 GCN layers: h = relu(gcn(BN(h))) ----
  hipMemsetAsync(statA, 0, 2 * 128 * 4, stream);
  k_stats<<<784, TPB, 0, stream>>>(A, N, 128, statA, 0, nullptr);
  for (int l = 0; l < 3; l++) {
    k_finalize<<<1, 256, 0, stream>>>(statA, N, 128);
    k_mm_bn<0><<<gMM, TPB, 0, stream>>>(A, statA, convW + (size_t)l * 128 * 128, B, N, 0, nullptr);
    hipMemsetAsync(statA, 0, 2 * 128 * 4, stream);
    if (l < 2)
      k_gconv_plain<1><<<2048, TPB, 0, stream>>>(B, dis2, row_start, csr_src, csr_coef, convB + l * 128, A, N, statA);
    else
      k_gconv_plain<0><<<2048, TPB, 0, stream>>>(B, dis2, row_start, csr_src, csr_coef, convB + l * 128, A, N, nullptr);
  }

  // ---- attention (edge + node) ----
  k_pqhn<<<1024, TPB, 0, stream>>>(A, eW, naW, PQ, hn, N);
  k_natt<<<gN, TPB, 0, stream>>>(hn, dis2, row_start, csr_src, csr_coef, nab, nlog, N);
  hipMemsetAsync(degA, 0, (size_t)N * 4, stream);
  hipMemsetAsync(degB, 0, (size_t)N * 4, stream);
  k_edge<<<gE, TPB, 0, stream>>>(esrc, edst, E, PQ, eb, attE, degA, degB);
  k_nodefin<<<gN, TPB, 0, stream>>>(degA, degB, nlog, disc, diso, selfcc, selfco, na0, N);
  k_edge2<<<gE, TPB, 0, stream>>>(esrc, edst, E, attE, edgepos, disc, diso, coefc, coefo);

  // ---- xc / xo BN stats (fused single pass over h) ----
  hipMemsetAsync(statA, 0, 2 * 128 * 4, stream);
  hipMemsetAsync(statB, 0, 2 * 128 * 4, stream);
  k_stats2<<<784, TPB, 0, stream>>>(A, N, statA, statB, na0);
  k_finalize<<<1, 256, 0, stream>>>(statA, N, 128);
  k_finalize<<<1, 256, 0, stream>>>(statB, N, 128);

  // ---- xc branch ----
  k_mm_bn<0><<<gMM, TPB, 0, stream>>>(A, statA, xcW, B, N, 1, na0);
  hipMemsetAsync(xc_g, 0, 512 * 128 * 4, stream);
  k_gconv_w_pool<<<2048, TPB, 0, stream>>>(B, selfcc, row_start, csr_src, coefc, xcb, batch, xc_g, N);
  // ---- xo branch ----
  k_mm_bn<0><<<gMM, TPB, 0, stream>>>(A, statB, xoW, B, N, 2, na0);
  hipMemsetAsync(xo_g, 0, 512 * 128 * 4, stream);
  k_gconv_w_pool<<<2048, TPB, 0, stream>>>(B, selfco, row_start, csr_src, coefo, xob, batch, xo_g, N);

  // ---- head C ----
  hipMemsetAsync(statA, 0, 2 * 128 * 4, stream);
  k_stats<<<16, TPB, 0, stream>>>(xc_g, 512, 128, statA, 0, nullptr);
  k_finalize<<<1, 256, 0, stream>>>(statA, 512, 128);
  k_mm_head<1><<<(512 * 128 + TPB - 1) / TPB, TPB, 0, stream>>>(xc_g, statA, 128, cW1, cb1, t1, 512, 128);
  hipMemsetAsync(statB, 0, 2 * 128 * 4, stream);
  k_stats<<<16, TPB, 0, stream>>>(t1, 512, 128, statB, 0, nullptr);
  k_finalize<<<1, 256, 0, stream>>>(statB, 512, 128);
  k_logits_lsm<<<2, TPB, 0, stream>>>(t1, statB, 128, cW2, cb2, out, 512);

  // ---- head O ----
  hipMemsetAsync(statA, 0, 2 * 128 * 4, stream);
  k_stats<<<16, TPB, 0, stream>>>(xo_g, 512, 128, statA, 0, nullptr);
  k_finalize<<<1, 256, 0, stream>>>(statA, 512, 128);
  k_mm_head<1><<<(512 * 128 + TPB - 1) / TPB, TPB, 0, stream>>>(xo_g, statA, 128, oW1, ob1, t1, 512, 128);
  hipMemsetAsync(statB, 0, 2 * 128 * 4, stream);
  k_stats<<<16, TPB, 0, stream>>>(t1, 512, 128, statB, 0, nullptr);
  k_finalize<<<1, 256, 0, stream>>>(statB, 512, 128);
  k_logits_lsm<<<2, TPB, 0, stream>>>(t1, statB, 128, oW2, ob2, out + 5120, 512);

  // ---- head CO ----
  k_concat<<<512, TPB, 0, stream>>>(xc_g, xo_g, co_in);
  hipMemsetAsync(statA, 0, 2 * 256 * 4, stream);
  k_stats<<<16, TPB, 0, stream>>>(co_in, 512, 256, statA, 0, nullptr);
  k_finalize<<<1, 256, 0, stream>>>(statA, 512, 256);
  k_mm_head<2><<<(512 * 128 + TPB - 1) / TPB, TPB, 0, stream>>>(co_in, statA, 256, coW1, cob1, t1, 512, 128);
  hipMemsetAsync(statB, 0, 2 * 128 * 4, stream);
  k_stats<<<16, TPB, 0, stream>>>(t1, 512, 128, statB, 0, nullptr);
  k_finalize<<<1, 256, 0, stream>>>(statB, 512, 128);
  k_logits_lsm<<<2, TPB, 0, stream>>>(t1, statB, 128, coW2, cob2, out + 10240, 512);
}

// Round 3
// 1201.055 us; speedup vs baseline: 1.2473x; 1.1934x over previous
//
#include <hip/hip_runtime.h>
#include <math.h>

#define EPS 1e-5f
#define BNB 1e-4f

typedef __attribute__((ext_vector_type(8))) short short8;
typedef __attribute__((ext_vector_type(4))) float f32x4;
typedef __attribute__((ext_vector_type(4))) unsigned short ushort4_t;

static __device__ __forceinline__ void atomAdd(float* p, float v) { unsafeAtomicAdd(p, v); }

static __device__ __forceinline__ unsigned short f2bf(float f) {
  unsigned u = __float_as_uint(f);
  unsigned r = (u + 0x7fffu + ((u >> 16) & 1u)) >> 16;
  return (unsigned short)r;
}
static __device__ __forceinline__ float bflo(unsigned u) { return __uint_as_float(u << 16); }
static __device__ __forceinline__ float bfhi(unsigned u) { return __uint_as_float(u & 0xffff0000u); }

// ---------------- column stats (sum, sumsq) ----------------
__global__ void k_stats(const float* __restrict__ X, int R, int C,
                        float* __restrict__ st)
{
  int T = gridDim.x * blockDim.x;
  int t = blockIdx.x * blockDim.x + threadIdx.x;
  int c = t % C;
  int r0 = t / C;
  int rs = T / C;
  float s = 0.f, s2 = 0.f;
  for (int r = r0; r < R; r += rs) {
    float v = X[(size_t)r * C + c];
    s += v; s2 += v * v;
  }
  atomAdd(&st[c], s);
  atomAdd(&st[C + c], s2);
}

// fused stats for xc = na0*h and xo = (1-na0)*h in one pass over h
__global__ void k_stats2(const float* __restrict__ X, int R,
                         float* __restrict__ stA, float* __restrict__ stB,
                         const float* __restrict__ na)
{
  const int C = 128;
  int T = gridDim.x * blockDim.x;
  int t = blockIdx.x * blockDim.x + threadIdx.x;
  int c = t % C; int r0 = t / C; int rs = T / C;
  float sa = 0, sa2 = 0, sb = 0, sb2 = 0;
  for (int r = r0; r < R; r += rs) {
    float v = X[(size_t)r * C + c];
    float a = na[r] * v;
    float b = (1.f - na[r]) * v;
    sa += a; sa2 += a * a; sb += b; sb2 += b * b;
  }
  atomAdd(&stA[c], sa); atomAdd(&stA[C + c], sa2);
  atomAdd(&stB[c], sb); atomAdd(&stB[C + c], sb2);
}

// st layout: [0,C) sum, [C,2C) sumsq, [2C,3C) mean, [3C,4C) rsqrt(var+eps)
__global__ void k_finalize(float* st, int R, int C)
{
  int c = blockIdx.x * blockDim.x + threadIdx.x;
  if (c < C) {
    float m = st[c] / R;
    float v = st[C + c] / R - m * m;
    st[2 * C + c] = m;
    st[3 * C + c] = rsqrtf(v + EPS);
  }
}

// ---------------- weight prep: W[k][n] f32 -> Wt bf16, transposed+swizzled ----------------
// Wt layout (ushort): addr(n,k) = n*128 + ((k>>3) ^ (n&7))*8 + (k&7)
__global__ void k_prepW(const float* __restrict__ W, unsigned short* __restrict__ Wt)
{
  int idx = blockIdx.x * 256 + threadIdx.x;  // 16384 elements
  int n = idx >> 7, k = idx & 127;
  float v = W[k * 128 + n];
  Wt[(n << 7) + (((k >> 3) ^ (n & 7)) << 3) + (k & 7)] = f2bf(v);
}

// ---------------- MFMA matmul: Out = act( BN(scale*A) @ W ), 64-row tiles ----------------
// sA layout (ushort): addr(r,k) = r*128 + ((k>>3) ^ (r&7))*8 + (k&7), same swizzle for sW.
template<int ACT, int OUTBF16, int STATS>   // ACT: 0 none, 1 relu
__global__ __launch_bounds__(256) void k_mm_mfma(
    const float* __restrict__ A, const float* __restrict__ st,
    const unsigned short* __restrict__ Wt, void* __restrict__ OutV,
    int Nrows, int scale_mode, const float* __restrict__ na,
    float* __restrict__ stOut)
{
  __shared__ unsigned short sA[64 * 128];
  __shared__ unsigned short sW[128 * 128];
  int t = threadIdx.x;
  int r0 = blockIdx.x * 64;

  // stage W: straight 32KB copy (Wt already transposed+swizzled)
  {
    const short8* src = (const short8*)Wt;
    short8* dst = (short8*)sW;
    #pragma unroll
    for (int j = 0; j < 8; j++) dst[t + 256 * j] = src[t + 256 * j];
  }
  // stage A with BN fused, f32 -> bf16
  {
    int r = t >> 2;
    int rg = r0 + r;
    bool valid = rg < Nrows;
    float sc = 1.f;
    if (scale_mode == 1) sc = valid ? na[rg] : 0.f;
    else if (scale_mode == 2) sc = valid ? (1.f - na[rg]) : 0.f;
    #pragma unroll
    for (int i = 0; i < 8; i++) {
      int k = ((t & 3) << 2) + (i << 4);
      float4 va = valid ? *(const float4*)(A + (size_t)rg * 128 + k)
                        : make_float4(0.f, 0.f, 0.f, 0.f);
      float4 mm = *(const float4*)(st + 256 + k);
      float4 iv = *(const float4*)(st + 384 + k);
      ushort4_t w;
      w.x = f2bf((sc * va.x - mm.x) * iv.x + BNB);
      w.y = f2bf((sc * va.y - mm.y) * iv.y + BNB);
      w.z = f2bf((sc * va.z - mm.z) * iv.z + BNB);
      w.w = f2bf((sc * va.w - mm.w) * iv.w + BNB);
      *(ushort4_t*)(&sA[(r << 7) + (((k >> 3) ^ (r & 7)) << 3) + (k & 7)]) = w;
    }
  }
  __syncthreads();

  int w = t >> 6, l = t & 63;
  int n0 = w * 32;
  int la = l & 15, hi = l >> 4;
  f32x4 acc[4][2];
  #pragma unroll
  for (int m = 0; m < 4; m++)
    #pragma unroll
    for (int nf = 0; nf < 2; nf++) {
      acc[m][nf][0] = 0.f; acc[m][nf][1] = 0.f;
      acc[m][nf][2] = 0.f; acc[m][nf][3] = 0.f;
    }

  #pragma unroll
  for (int ks = 0; ks < 4; ks++) {
    int slot = ks * 4 + hi;          // = (ks*32 + hi*8) >> 3
    short8 af[4], bfr[2];
    #pragma unroll
    for (int m = 0; m < 4; m++) {
      int r = 16 * m + la;
      af[m] = *(const short8*)(&sA[(r << 7) + ((slot ^ (r & 7)) << 3)]);
    }
    #pragma unroll
    for (int nf = 0; nf < 2; nf++) {
      int n = n0 + 16 * nf + la;
      bfr[nf] = *(const short8*)(&sW[(n << 7) + ((slot ^ (n & 7)) << 3)]);
    }
    #pragma unroll
    for (int m = 0; m < 4; m++)
      #pragma unroll
      for (int nf = 0; nf < 2; nf++)
        acc[m][nf] = __builtin_amdgcn_mfma_f32_16x16x32_bf16(af[m], bfr[nf], acc[m][nf], 0, 0, 0);
  }

  // epilogue: D layout col = lane&15, row = (lane>>4)*4 + reg
  #pragma unroll
  for (int nf = 0; nf < 2; nf++) {
    int c = n0 + 16 * nf + la;
    float scol = 0.f, qcol = 0.f;
    #pragma unroll
    for (int m = 0; m < 4; m++) {
      #pragma unroll
      for (int q = 0; q < 4; q++) {
        int r = r0 + 16 * m + hi * 4 + q;
        float v = acc[m][nf][q];
        if (ACT == 1) v = fmaxf(v, 0.f);
        if (r < Nrows) {
          if (OUTBF16) ((unsigned short*)OutV)[(size_t)r * 128 + c] = f2bf(v);
          else         ((float*)OutV)[(size_t)r * 128 + c] = v;
          if (STATS) { scol += v; qcol += v * v; }
        }
      }
    }
    if (STATS) {
      scol += __shfl_xor(scol, 16); scol += __shfl_xor(scol, 32);
      qcol += __shfl_xor(qcol, 16); qcol += __shfl_xor(qcol, 32);
      if (hi == 0) { atomAdd(&stOut[c], scol); atomAdd(&stOut[128 + c], qcol); }
    }
  }
}

// ---------------- graph structure ----------------
__global__ void k_hist_f(const int* __restrict__ idx, int E, float* __restrict__ deg)
{
  int e = blockIdx.x * blockDim.x + threadIdx.x;
  if (e < E) atomAdd(&deg[idx[e]], 1.f);
}
__global__ void k_hist_i(const int* __restrict__ idx, int E, int* __restrict__ cnt)
{
  int e = blockIdx.x * blockDim.x + threadIdx.x;
  if (e < E) atomicAdd(&cnt[idx[e]], 1);
}
__global__ void k_rsqrt1(const float* __restrict__ deg, float* __restrict__ dis,
                         float* __restrict__ dis2, int Nn)
{
  int i = blockIdx.x * blockDim.x + threadIdx.x;
  if (i < Nn) {
    float d = rsqrtf(deg[i] + 1.f);
    dis[i] = d;
    dis2[i] = d * d;
  }
}
// single-block exclusive scan over (cnt[i] + 1)  — +1 reserves the self-edge slot
__global__ void k_scan(const int* __restrict__ cnt, int Nn, int* __restrict__ row_start)
{
  __shared__ int sd[1024];
  __shared__ int srun;
  int t = threadIdx.x;
  if (t == 0) srun = 0;
  __syncthreads();
  for (int base = 0; base < Nn; base += 1024) {
    int v = (base + t < Nn) ? cnt[base + t] + 1 : 0;
    sd[t] = v;
    __syncthreads();
    for (int off = 1; off < 1024; off <<= 1) {
      int x = (t >= off) ? sd[t - off] : 0;
      __syncthreads();
      sd[t] += x;
      __syncthreads();
    }
    int incl = sd[t];
    int run = srun;
    if (base + t < Nn) row_start[base + t] = run + incl - v;
    __syncthreads();
    if (t == 1023) srun = run + incl;
    __syncthreads();
  }
  if (t == 0) row_start[Nn] = srun;
}
// fill CSR data edges at slot 1+; (idx, coef) packed as int2
__global__ void k_fill(const int* __restrict__ src, const int* __restrict__ dst, int E,
                       const int* __restrict__ row_start, int* __restrict__ cnt,
                       const float* __restrict__ dis,
                       int2* __restrict__ icP, int* __restrict__ edgepos)
{
  int e = blockIdx.x * blockDim.x + threadIdx.x;
  if (e >= E) return;
  int d = dst[e];
  int s = src[e];
  int k = atomicAdd(&cnt[d], 1);
  int pos = row_start[d] + 1 + k;
  icP[pos] = make_int2(s, __float_as_int(dis[s] * dis[d]));
  edgepos[e] = pos;
}
// self edge at slot 0 of each row
__global__ void k_fillself(const int* __restrict__ row_start, const float* __restrict__ dis2,
                           int2* __restrict__ icP, int Nn)
{
  int i = blockIdx.x * blockDim.x + threadIdx.x;
  if (i < Nn) icP[row_start[i]] = make_int2(i, __float_as_int(dis2[i]));
}

// ---------------- unified gather: 2 nodes/iter, bf16 rows, self folded into CSR ----------------
template<int MODE>  // 0: relu+out+stats, 1: relu+out, 2: elu+pool
__global__ __launch_bounds__(256) void k_gconv2(
    const unsigned short* __restrict__ Hb, const int* __restrict__ rs,
    const int2* __restrict__ ic, const float* __restrict__ bias,
    float* __restrict__ Out, const int* __restrict__ batch,
    float* __restrict__ outg, int Nn, float* __restrict__ st)
{
  __shared__ float red[1024];
  int t = threadIdx.x, lane = t & 63;
  int c0 = lane * 2;
  int wid = (blockIdx.x * 256 + t) >> 6;
  int nw = (gridDim.x * 256) >> 6;
  int chunk = (Nn + nw - 1) / nw;
  int i0 = wid * chunk, i1 = min(Nn, i0 + chunk);
  float b0 = bias[c0], b1 = bias[c0 + 1];
  float s0 = 0, s1 = 0, q0 = 0, q1 = 0;
  int curg = -1; float gx = 0.f, gy = 0.f;
  for (int i = i0; i < i1; i += 2) {
    bool hasB = (i + 1 < i1);
    int jbA = rs[i];
    int jeA = rs[i + 1];
    int jeB = hasB ? rs[i + 2] : jeA;
    float aAx = b0, aAy = b1, aBx = b0, aBy = b1;
    for (int base = jbA; base < jeB; base += 64) {
      int pos = base + lane;
      int ix = 0, cfb = 0;
      if (pos < jeB) { int2 v = ic[pos]; ix = v.x; cfb = v.y; }
      int nj = min(jeB - base, 64);
      for (int j = 0; j < nj; j += 8) {
        int i_[8]; float cA_[8], cB_[8];
        #pragma unroll
        for (int q = 0; q < 8; q++) {
          int jj = j + q;
          int ii = __shfl(ix, jj);
          float cf = __int_as_float(__shfl(cfb, jj));
          bool ownA = (base + jj) < jeA;
          i_[q] = ii;
          cA_[q] = ownA ? cf : 0.f;
          cB_[q] = ownA ? 0.f : cf;
        }
        unsigned u_[8];
        #pragma unroll
        for (int q = 0; q < 8; q++)
          u_[q] = *(const unsigned*)(Hb + (size_t)i_[q] * 128 + c0);
        #pragma unroll
        for (int q = 0; q < 8; q++) {
          float ux = bflo(u_[q]), uy = bfhi(u_[q]);
          aAx = fmaf(cA_[q], ux, aAx); aAy = fmaf(cA_[q], uy, aAy);
          aBx = fmaf(cB_[q], ux, aBx); aBy = fmaf(cB_[q], uy, aBy);
        }
      }
    }
    if (MODE < 2) {
      aAx = fmaxf(aAx, 0.f); aAy = fmaxf(aAy, 0.f);
      *(float2*)(Out + (size_t)i * 128 + c0) = make_float2(aAx, aAy);
      if (MODE == 0) { s0 += aAx; s1 += aAy; q0 += aAx * aAx; q1 += aAy * aAy; }
      if (hasB) {
        aBx = fmaxf(aBx, 0.f); aBy = fmaxf(aBy, 0.f);
        *(float2*)(Out + (size_t)(i + 1) * 128 + c0) = make_float2(aBx, aBy);
        if (MODE == 0) { s0 += aBx; s1 += aBy; q0 += aBx * aBx; q1 += aBy * aBy; }
      }
    } else {
      aAx = aAx > 0.f ? aAx : expm1f(aAx);
      aAy = aAy > 0.f ? aAy : expm1f(aAy);
      int g = batch[i];
      if (g != curg) {
        if (curg >= 0) { atomAdd(&outg[curg * 128 + c0], gx); atomAdd(&outg[curg * 128 + c0 + 1], gy); }
        curg = g; gx = aAx; gy = aAy;
      } else { gx += aAx; gy += aAy; }
      if (hasB) {
        aBx = aBx > 0.f ? aBx : expm1f(aBx);
        aBy = aBy > 0.f ? aBy : expm1f(aBy);
        int g2 = batch[i + 1];
        if (g2 != curg) {
          if (curg >= 0) { atomAdd(&outg[curg * 128 + c0], gx); atomAdd(&outg[curg * 128 + c0 + 1], gy); }
          curg = g2; gx = aBx; gy = aBy;
        } else { gx += aBx; gy += aBy; }
      }
    }
  }
  if (MODE == 2) {
    if (curg >= 0) { atomAdd(&outg[curg * 128 + c0], gx); atomAdd(&outg[curg * 128 + c0 + 1], gy); }
  }
  if (MODE == 0) {
    red[t] = s0; red[256 + t] = s1; red[512 + t] = q0; red[768 + t] = q1;
    __syncthreads();
    if (t < 64) {
      float a0 = red[t] + red[t + 64] + red[t + 128] + red[t + 192];
      float a1 = red[256 + t] + red[256 + t + 64] + red[256 + t + 128] + red[256 + t + 192];
      float a2 = red[512 + t] + red[512 + t + 64] + red[512 + t + 128] + red[512 + t + 192];
      float a3 = red[768 + t] + red[768 + t + 64] + red[768 + t + 128] + red[768 + t + 192];
      atomAdd(&st[2 * t], a0); atomAdd(&st[2 * t + 1], a1);
      atomAdd(&st[128 + 2 * t], a2); atomAdd(&st[128 + 2 * t + 1], a3);
    }
  }
}

// ---------------- per-node projections: P,Q (edge MLP halves) and hn = h@naW ----------------
__global__ __launch_bounds__(256) void k_pqhn(
    const float* __restrict__ H, const float* __restrict__ eW,
    const float* __restrict__ naW, float4* __restrict__ PQ,
    float2* __restrict__ hn, int Nn)
{
  __shared__ float w[128][6];
  int t = threadIdx.x;
  if (t < 128) {
    w[t][0] = eW[2 * t];       w[t][1] = eW[2 * t + 1];
    w[t][2] = eW[256 + 2 * t]; w[t][3] = eW[256 + 2 * t + 1];
    w[t][4] = naW[2 * t];      w[t][5] = naW[2 * t + 1];
  }
  __syncthreads();
  int lane = t & 63;
  int wid = (blockIdx.x * 256 + t) >> 6;
  int nw = (gridDim.x * 256) >> 6;
  for (int i = wid; i < Nn; i += nw) {
    const float2 h2 = *(const float2*)(H + (size_t)i * 128 + lane * 2);
    int k0 = lane * 2, k1 = lane * 2 + 1;
    float p0 = h2.x * w[k0][0] + h2.y * w[k1][0];
    float p1 = h2.x * w[k0][1] + h2.y * w[k1][1];
    float q0 = h2.x * w[k0][2] + h2.y * w[k1][2];
    float q1 = h2.x * w[k0][3] + h2.y * w[k1][3];
    float n0 = h2.x * w[k0][4] + h2.y * w[k1][4];
    float n1 = h2.x * w[k0][5] + h2.y * w[k1][5];
    #pragma unroll
    for (int o = 32; o > 0; o >>= 1) {
      p0 += __shfl_xor(p0, o); p1 += __shfl_xor(p1, o);
      q0 += __shfl_xor(q0, o); q1 += __shfl_xor(q1, o);
      n0 += __shfl_xor(n0, o); n1 += __shfl_xor(n1, o);
    }
    if (lane == 0) {
      PQ[i] = make_float4(p0, p1, q0, q1);
      hn[i] = make_float2(n0, n1);
    }
  }
}

// node-att propagate (2 channels; self edge already in CSR)
__global__ void k_natt(const float2* __restrict__ hn,
                       const int* __restrict__ rs, const int2* __restrict__ icP,
                       const float* __restrict__ nab, float2* __restrict__ nlog, int Nn)
{
  int i = blockIdx.x * blockDim.x + threadIdx.x;
  if (i >= Nn) return;
  float a0 = nab[0];
  float a1 = nab[1];
  int jb = rs[i], je = rs[i + 1];
  for (int j = jb; j < je; j++) {
    int2 v = icP[j];
    float c = __int_as_float(v.y);
    float2 hs = hn[v.x];
    a0 += c * hs.x;
    a1 += c * hs.y;
  }
  nlog[i] = make_float2(a0, a1);
}

// per-edge attention + weighted-degree accumulation
__global__ void k_edge(const int* __restrict__ src, const int* __restrict__ dst, int E,
                       const float4* __restrict__ PQ, const float* __restrict__ eb,
                       float* __restrict__ attE,
                       float* __restrict__ degc, float* __restrict__ dego)
{
  int e = blockIdx.x * blockDim.x + threadIdx.x;
  if (e >= E) return;
  int s = src[e], d = dst[e];
  float4 ps = PQ[s];
  float4 pd = PQ[d];
  float ld = (ps.x - ps.y) + (pd.z - pd.w) + (eb[0] - eb[1]);
  float att = 1.f / (1.f + expf(-ld));
  attE[e] = att;
  atomAdd(&degc[s], att);
  atomAdd(&dego[s], 1.f - att);
}

__global__ void k_nodefin(const float* __restrict__ degc, const float* __restrict__ dego,
                          const float2* __restrict__ nlog,
                          float* __restrict__ disc, float* __restrict__ diso,
                          float* __restrict__ selfcc, float* __restrict__ selfco,
                          float* __restrict__ na0, int Nn)
{
  int i = blockIdx.x * blockDim.x + threadIdx.x;
  if (i >= Nn) return;
  float dc = rsqrtf(degc[i] + 1.f);
  float dd = rsqrtf(dego[i] + 1.f);
  disc[i] = dc; diso[i] = dd;
  selfcc[i] = dc * dc; selfco[i] = dd * dd;
  float2 l = nlog[i];
  na0[i] = 1.f / (1.f + expf(-(l.x - l.y)));
}

// per-edge weighted (idx,coef) pairs into CSR order
__global__ void k_edge2(const int* __restrict__ src, const int* __restrict__ dst, int E,
                        const float* __restrict__ attE, const int* __restrict__ edgepos,
                        const float* __restrict__ disc, const float* __restrict__ diso,
                        int2* __restrict__ icC, int2* __restrict__ icO)
{
  int e = blockIdx.x * blockDim.x + threadIdx.x;
  if (e >= E) return;
  int s = src[e], d = dst[e];
  int pos = edgepos[e];
  float att = attE[e];
  icC[pos] = make_int2(s, __float_as_int(disc[s] * att * disc[d]));
  icO[pos] = make_int2(s, __float_as_int(diso[s] * (1.f - att) * diso[d]));
}
// weighted self slots
__global__ void k_selfw(const int* __restrict__ row_start,
                        const float* __restrict__ selfcc, const float* __restrict__ selfco,
                        int2* __restrict__ icC, int2* __restrict__ icO, int Nn)
{
  int i = blockIdx.x * blockDim.x + threadIdx.x;
  if (i >= Nn) return;
  int p = row_start[i];
  icC[p] = make_int2(i, __float_as_int(selfcc[i]));
  icO[p] = make_int2(i, __float_as_int(selfco[i]));
}

// ---------------- heads ----------------
template<int ACT>  // 0 none, 1 relu, 2 elu(elu(.))
__global__ void k_mm_head(const float* __restrict__ In, const float* __restrict__ st, int K,
                          const float* __restrict__ W, const float* __restrict__ bias,
                          float* __restrict__ Out, int M, int Ncol)
{
  int idx = blockIdx.x * blockDim.x + threadIdx.x;
  if (idx >= M * Ncol) return;
  int r = idx / Ncol, c = idx % Ncol;
  const float* mean = st + 2 * K;
  const float* inv  = st + 3 * K;
  float acc = bias[c];
  for (int k = 0; k < K; k++) {
    float a = (In[(size_t)r * K + k] - mean[k]) * inv[k] + BNB;
    acc += a * W[(size_t)k * Ncol + c];
  }
  if (ACT == 1) acc = fmaxf(acc, 0.f);
  if (ACT == 2) {
    acc = acc > 0.f ? acc : expm1f(acc);
    acc = acc > 0.f ? acc : expm1f(acc);
  }
  Out[idx] = acc;
}

__global__ void k_logits_lsm(const float* __restrict__ In, const float* __restrict__ st, int K,
                             const float* __restrict__ W, const float* __restrict__ bias,
                             float* __restrict__ Out, int M)
{
  int r = blockIdx.x * blockDim.x + threadIdx.x;
  if (r >= M) return;
  const float* mean = st + 2 * K;
  const float* inv  = st + 3 * K;
  float l[10];
  #pragma unroll
  for (int j = 0; j < 10; j++) l[j] = bias[j];
  for (int k = 0; k < K; k++) {
    float a = (In[(size_t)r * K + k] - mean[k]) * inv[k] + BNB;
    #pragma unroll
    for (int j = 0; j < 10; j++) l[j] += a * W[k * 10 + j];
  }
  float mx = l[0];
  #pragma unroll
  for (int j = 1; j < 10; j++) mx = fmaxf(mx, l[j]);
  float se = 0.f;
  #pragma unroll
  for (int j = 0; j < 10; j++) se += expf(l[j] - mx);
  float lse = mx + logf(se);
  #pragma unroll
  for (int j = 0; j < 10; j++) Out[r * 10 + j] = l[j] - lse;
}

__global__ void k_concat(const float* __restrict__ a, const float* __restrict__ b,
                         float* __restrict__ o)
{
  int idx = blockIdx.x * blockDim.x + threadIdx.x;
  if (idx >= 512 * 256) return;
  int r = idx >> 8, c = idx & 255;
  o[idx] = (c < 128) ? a[r * 128 + c] : b[r * 128 + (c - 128)];
}

// =====================================================================
extern "C" void kernel_launch(void* const* d_in, const int* in_sizes, int n_in,
                              void* d_out, int out_size, void* d_ws, size_t ws_size,
                              hipStream_t stream)
{
  (void)n_in; (void)out_size; (void)ws_size;
  const float* x      = (const float*)d_in[0];
  const float* W_feat = (const float*)d_in[1];
  const float* convW  = (const float*)d_in[2];
  const float* convB  = (const float*)d_in[3];
  const float* eW     = (const float*)d_in[4];
  const float* eb     = (const float*)d_in[5];
  const float* naW    = (const float*)d_in[6];
  const float* nab    = (const float*)d_in[7];
  const float* xcW    = (const float*)d_in[8];
  const float* xcb    = (const float*)d_in[9];
  const float* xoW    = (const float*)d_in[10];
  const float* xob    = (const float*)d_in[11];
  const float* cW1    = (const float*)d_in[12];
  const float* cb1    = (const float*)d_in[13];
  const float* cW2    = (const float*)d_in[14];
  const float* cb2    = (const float*)d_in[15];
  const float* oW1    = (const float*)d_in[16];
  const float* ob1    = (const float*)d_in[17];
  const float* oW2    = (const float*)d_in[18];
  const float* ob2    = (const float*)d_in[19];
  const float* coW1   = (const float*)d_in[20];
  const float* cob1   = (const float*)d_in[21];
  const float* coW2   = (const float*)d_in[22];
  const float* cob2   = (const float*)d_in[23];
  const int* esrc  = (const int*)d_in[24];
  const int* edst  = (const int*)d_in[25];
  const int* batch = (const int*)d_in[26];
  const int E = in_sizes[24];
  const int N = in_sizes[26];
  float* out = (float*)d_out;

  char* wp = (char*)d_ws;
  auto alloc = [&](size_t bytes) -> char* {
    char* p = wp;
    wp += (bytes + 255) & ~size_t(255);
    return p;
  };
  float*  A        = (float*)alloc((size_t)N * 128 * 4);
  unsigned short* Bb = (unsigned short*)alloc((size_t)N * 128 * 2);
  float*  dis      = (float*)alloc((size_t)N * 4);
  float*  dis2     = (float*)alloc((size_t)N * 4);
  float*  disc     = (float*)alloc((size_t)N * 4);
  float*  diso     = (float*)alloc((size_t)N * 4);
  float*  selfcc   = (float*)alloc((size_t)N * 4);
  float*  selfco   = (float*)alloc((size_t)N * 4);
  float*  na0      = (float*)alloc((size_t)N * 4);
  float4* PQ       = (float4*)alloc((size_t)N * 16);
  float2* hn       = (float2*)alloc((size_t)N * 8);
  float2* nlog     = (float2*)alloc((size_t)N * 8);
  float*  degA     = (float*)alloc((size_t)N * 4);
  float*  degB     = (float*)alloc((size_t)N * 4);
  int*    cnt      = (int*)alloc((size_t)N * 4);
  int*    row_start= (int*)alloc((size_t)(N + 1) * 4);
  int2*   icP      = (int2*)alloc((size_t)(E + N) * 8);
  int2*   icC      = (int2*)alloc((size_t)(E + N) * 8);
  int2*   icO      = (int2*)alloc((size_t)(E + N) * 8);
  float*  attE     = (float*)alloc((size_t)E * 4);
  int*    edgepos  = (int*)alloc((size_t)E * 4);
  unsigned short* WtF = (unsigned short*)alloc(16384 * 2);
  unsigned short* Wt0 = (unsigned short*)alloc(16384 * 2);
  unsigned short* Wt1 = (unsigned short*)alloc(16384 * 2);
  unsigned short* Wt2 = (unsigned short*)alloc(16384 * 2);
  unsigned short* WtC = (unsigned short*)alloc(16384 * 2);
  unsigned short* WtO = (unsigned short*)alloc(16384 * 2);
  float*  statA    = (float*)alloc(4 * 256 * 4);
  float*  statB    = (float*)alloc(4 * 256 * 4);
  float*  xc_g     = (float*)alloc(512 * 128 * 4);
  float*  xo_g     = (float*)alloc(512 * 128 * 4);
  float*  co_in    = (float*)alloc(512 * 256 * 4);
  float*  t1       = (float*)alloc(512 * 128 * 4);

  const int TPB = 256;
  int gE  = (E + TPB - 1) / TPB;
  int gN  = (N + TPB - 1) / TPB;
  int gMM = (N + 63) / 64;

  // ---- graph structure ----
  hipMemsetAsync(degA, 0, (size_t)N * 4, stream);
  k_hist_f<<<gE, TPB, 0, stream>>>(esrc, E, degA);
  k_rsqrt1<<<gN, TPB, 0, stream>>>(degA, dis, dis2, N);
  hipMemsetAsync(cnt, 0, (size_t)N * 4, stream);
  k_hist_i<<<gE, TPB, 0, stream>>>(edst, E, cnt);
  k_scan<<<1, 1024, 0, stream>>>(cnt, N, row_start);
  hipMemsetAsync(cnt, 0, (size_t)N * 4, stream);
  k_fill<<<gE, TPB, 0, stream>>>(esrc, edst, E, row_start, cnt, dis, icP, edgepos);
  k_fillself<<<gN, TPB, 0, stream>>>(row_start, dis2, icP, N);

  // ---- weight prep (bf16, transposed+swizzled) ----
  k_prepW<<<64, TPB, 0, stream>>>(W_feat, WtF);
  k_prepW<<<64, TPB, 0, stream>>>(convW, Wt0);
  k_prepW<<<64, TPB, 0, stream>>>(convW + 128 * 128, Wt1);
  k_prepW<<<64, TPB, 0, stream>>>(convW + 2 * 128 * 128, Wt2);
  k_prepW<<<64, TPB, 0, stream>>>(xcW, WtC);
  k_prepW<<<64, TPB, 0, stream>>>(xoW, WtO);

  // ---- h = relu(BN(x) @ W_feat), fused stats of h -> statB ----
  hipMemsetAsync(statA, 0, 2 * 128 * 4, stream);
  k_stats<<<784, TPB, 0, stream>>>(x, N, 128, statA);
  k_finalize<<<1, 256, 0, stream>>>(statA, N, 128);
  hipMemsetAsync(statB, 0, 2 * 128 * 4, stream);
  k_mm_mfma<1, 0, 1><<<gMM, TPB, 0, stream>>>(x, statA, WtF, A, N, 0, nullptr, statB);

  // ---- 3 GCN layers: h = relu(gcn(BN(h))) ----
  const unsigned short* Wts[3] = {Wt0, Wt1, Wt2};
  for (int l = 0; l < 3; l++) {
    k_finalize<<<1, 256, 0, stream>>>(statB, N, 128);
    k_mm_mfma<0, 1, 0><<<gMM, TPB, 0, stream>>>(A, statB, Wts[l], Bb, N, 0, nullptr, nullptr);
    hipMemsetAsync(statB, 0, 2 * 128 * 4, stream);
    if (l < 2)
      k_gconv2<0><<<2048, TPB, 0, stream>>>(Bb, row_start, icP, convB + l * 128, A, nullptr, nullptr, N, statB);
    else
      k_gconv2<1><<<2048, TPB, 0, stream>>>(Bb, row_start, icP, convB + l * 128, A, nullptr, nullptr, N, nullptr);
  }

  // ---- attention (edge + node) ----
  k_pqhn<<<1024, TPB, 0, stream>>>(A, eW, naW, PQ, hn, N);
  k_natt<<<gN, TPB, 0, stream>>>(hn, row_start, icP, nab, nlog, N);
  hipMemsetAsync(degA, 0, (size_t)N * 4, stream);
  hipMemsetAsync(degB, 0, (size_t)N * 4, stream);
  k_edge<<<gE, TPB, 0, stream>>>(esrc, edst, E, PQ, eb, attE, degA, degB);
  k_nodefin<<<gN, TPB, 0, stream>>>(degA, degB, nlog, disc, diso, selfcc, selfco, na0, N);
  k_edge2<<<gE, TPB, 0, stream>>>(esrc, edst, E, attE, edgepos, disc, diso, icC, icO);
  k_selfw<<<gN, TPB, 0, stream>>>(row_start, selfcc, selfco, icC, icO, N);

  // ---- xc / xo BN stats (fused single pass over h) ----
  hipMemsetAsync(statA, 0, 2 * 128 * 4, stream);
  hipMemsetAsync(statB, 0, 2 * 128 * 4, stream);
  k_stats2<<<784, TPB, 0, stream>>>(A, N, statA, statB, na0);
  k_finalize<<<1, 256, 0, stream>>>(statA, N, 128);
  k_finalize<<<1, 256, 0, stream>>>(statB, N, 128);

  // ---- xc branch ----
  k_mm_mfma<0, 1, 0><<<gMM, TPB, 0, stream>>>(A, statA, WtC, Bb, N, 1, na0, nullptr);
  hipMemsetAsync(xc_g, 0, 512 * 128 * 4, stream);
  k_gconv2<2><<<2048, TPB, 0, stream>>>(Bb, row_start, icC, xcb, nullptr, batch, xc_g, N, nullptr);
  // ---- xo branch ----
  k_mm_mfma<0, 1, 0><<<gMM, TPB, 0, stream>>>(A, statB, WtO, Bb, N, 2, na0, nullptr);
  hipMemsetAsync(xo_g, 0, 512 * 128 * 4, stream);
  k_gconv2<2><<<2048, TPB, 0, stream>>>(Bb, row_start, icO, xob, nullptr, batch, xo_g, N, nullptr);

  // ---- head C ----
  hipMemsetAsync(statA, 0, 2 * 128 * 4, stream);
  k_stats<<<16, TPB, 0, stream>>>(xc_g, 512, 128, statA);
  k_finalize<<<1, 256, 0, stream>>>(statA, 512, 128);
  k_mm_head<1><<<(512 * 128 + TPB - 1) / TPB, TPB, 0, stream>>>(xc_g, statA, 128, cW1, cb1, t1, 512, 128);
  hipMemsetAsync(statB, 0, 2 * 128 * 4, stream);
  k_stats<<<16, TPB, 0, stream>>>(t1, 512, 128, statB);
  k_finalize<<<1, 256, 0, stream>>>(statB, 512, 128);
  k_logits_lsm<<<2, TPB, 0, stream>>>(t1, statB, 128, cW2, cb2, out, 512);

  // ---- head O ----
  hipMemsetAsync(statA, 0, 2 * 128 * 4, stream);
  k_stats<<<16, TPB, 0, stream>>>(xo_g, 512, 128, statA);
  k_finalize<<<1, 256, 0, stream>>>(statA, 512, 128);
  k_mm_head<1><<<(512 * 128 + TPB - 1) / TPB, TPB, 0, stream>>>(xo_g, statA, 128, oW1, ob1, t1, 512, 128);
  hipMemsetAsync(statB, 0, 2 * 128 * 4, stream);
  k_stats<<<16, TPB, 0, stream>>>(t1, 512, 128, statB);
  k_finalize<<<1, 256, 0, stream>>>(statB, 512, 128);
  k_logits_lsm<<<2, TPB, 0, stream>>>(t1, statB, 128, oW2, ob2, out + 5120, 512);

  // ---- head CO ----
  k_concat<<<512, TPB, 0, stream>>>(xc_g, xo_g, co_in);
  hipMemsetAsync(statA, 0, 2 * 256 * 4, stream);
  k_stats<<<16, TPB, 0, stream>>>(co_in, 512, 256, statA);
  k_finalize<<<1, 256, 0, stream>>>(statA, 512, 256);
  k_mm_head<2><<<(512 * 128 + TPB - 1) / TPB, TPB, 0, stream>>>(co_in, statA, 256, coW1, cob1, t1, 512, 128);
  hipMemsetAsync(statB, 0, 2 * 128 * 4, stream);
  k_stats<<<16, TPB, 0, stream>>>(t1, 512, 128, statB);
  k_finalize<<<1, 256, 0, stream>>>(statB, 512, 128);
  k_logits_lsm<<<2, TPB, 0, stream>>>(t1, statB, 128, coW2, cob2, out + 10240, 512);
}